// Round 5
// baseline (344.147 us; speedup 1.0000x reference)
//
#include <hip/hip_runtime.h>

// Problem constants
constexpr int B    = 8;
constexpr int N    = 4096;
constexpr int CIN  = 6;
constexpr int NC   = 3;
constexpr int NP   = 1024;
constexpr int C0   = CIN + NC;   // 9
constexpr int M1   = 64;
constexpr int M2   = 64;
constexpr int M3   = 128;
constexpr int NPTS = B * NP;     // 8192
constexpr int NPB  = 32;         // partial blocks per channel
constexpr float EPS = 1e-5f;

constexpr int GRID = 512;        // fused kernel grid (co-residency proven below)
constexpr int T    = 256;

// d_out layout: [grouped_xyz zeros: 6 MB] ++ [pooled: B*M3*NP]
constexpr int GZ_ELEMS = B * NP * 64 * 3;   // 1,572,864 floats
constexpr int GZ_F4    = GZ_ELEMS / 4;      // 393,216 float4

// d_ws layout (floats)
constexpr size_t Y1_OFF  = 0;
constexpr size_t Y2_OFF  = Y1_OFF + (size_t)M1 * NPTS;
constexpr size_t Y3_OFF  = Y2_OFF + (size_t)M2 * NPTS;
constexpr size_t PS1_OFF = Y3_OFF + (size_t)M3 * NPTS;
constexpr size_t PQ1_OFF = PS1_OFF + M1 * NPB;
constexpr size_t PS2_OFF = PQ1_OFF + M1 * NPB;
constexpr size_t PQ2_OFF = PS2_OFF + M2 * NPB;
constexpr size_t PS3_OFF = PQ2_OFF + M2 * NPB;
constexpr size_t PQ3_OFF = PS3_OFF + M3 * NPB;
constexpr size_t BAR_OFF = PQ3_OFF + M3 * NPB;   // 8 uints

// ---- node 1: zero the grid-barrier counters (d_ws is poisoned 0xAA) ----
__global__ void k0_init(unsigned* __restrict__ bar) {
    if (threadIdx.x < 8) bar[threadIdx.x] = 0u;
}

// ---- device-scope grid barrier (all GRID blocks co-resident) ----
__device__ inline void grid_bar(unsigned* __restrict__ bar, int bi) {
    __syncthreads();
    if (threadIdx.x == 0) {
        __threadfence();  // release: flush our writes (cross-XCD visible)
        __hip_atomic_fetch_add(&bar[bi], 1u, __ATOMIC_ACQ_REL, __HIP_MEMORY_SCOPE_AGENT);
        long tries = 0;
        while (__hip_atomic_load(&bar[bi], __ATOMIC_ACQUIRE, __HIP_MEMORY_SCOPE_AGENT)
               < (unsigned)GRID) {
            __builtin_amdgcn_s_sleep(2);
            if (++tries > (1L << 27)) break;   // safety valve: never hang the queue
        }
        __threadfence();  // acquire: invalidate stale L1/L2 before consuming
    }
    __syncthreads();
}

// ---- deterministic per-block partial sums (8 channels) ----
__device__ inline void emit_partials8(const float (&acc)[8], int o0, int pb,
                                      float* __restrict__ ps, float* __restrict__ pq) {
    __shared__ float rs[8][4], rq[8][4];
    __syncthreads();   // guard reuse of rs/rq across calls
    float sv[8], qv[8];
#pragma unroll
    for (int o = 0; o < 8; ++o) { sv[o] = acc[o]; qv[o] = acc[o] * acc[o]; }
#pragma unroll
    for (int off = 32; off; off >>= 1) {
#pragma unroll
        for (int o = 0; o < 8; ++o) {
            sv[o] += __shfl_down(sv[o], off, 64);
            qv[o] += __shfl_down(qv[o], off, 64);
        }
    }
    int lane = threadIdx.x & 63, w = threadIdx.x >> 6;
    if (lane == 0) {
#pragma unroll
        for (int o = 0; o < 8; ++o) { rs[o][w] = sv[o]; rq[o][w] = qv[o]; }
    }
    __syncthreads();
    if (threadIdx.x < 8) {
        int o = threadIdx.x;
        float s = rs[o][0] + rs[o][1] + rs[o][2] + rs[o][3];
        float q = rq[o][0] + rq[o][1] + rq[o][2] + rq[o][3];
        ps[(o0 + o) * NPB + pb] = s;
        pq[(o0 + o) * NPB + pb] = q;
    }
}

// ---- fold 64-channel partials into per-channel A,B (threads 0..63) ----
__device__ inline void fold_AB64(const float* __restrict__ ps, const float* __restrict__ pq,
                                 const float* __restrict__ gamma, const float* __restrict__ beta,
                                 float* __restrict__ sAB) {
    int t = threadIdx.x;
    if (t < 64) {
        float s = 0.f, q = 0.f;
#pragma unroll 8
        for (int i = 0; i < NPB; ++i) { s += ps[t * NPB + i]; q += pq[t * NPB + i]; }
        float inv_n = 1.0f / (float)NPTS;
        float mean = s * inv_n;
        float var  = q * inv_n - mean * mean;
        float A = gamma[t] * rsqrtf(var + EPS);
        sAB[2 * t]     = A;
        sAB[2 * t + 1] = beta[t] - mean * A;
    }
}

// ---- the fused persistent kernel: all 3 MLP stages + zero-fill + pooled out ----
__global__ __launch_bounds__(T, 2)   // VGPR<=256 => worst-case 2 blocks/CU => 512 co-resident
void k_fused(const float* __restrict__ points,
             const float* __restrict__ onehot,
             const int*   __restrict__ idx,
             const float* __restrict__ w1,
             const float* __restrict__ g1, const float* __restrict__ b1,
             const float* __restrict__ w2,
             const float* __restrict__ g2, const float* __restrict__ b2,
             const float* __restrict__ w3,
             const float* __restrict__ g3, const float* __restrict__ b3,
             float* __restrict__ ws, float* __restrict__ out) {
    float* y1  = ws + Y1_OFF;
    float* y2  = ws + Y2_OFF;
    float* y3  = ws + Y3_OFF;
    float* ps1 = ws + PS1_OFF;  float* pq1 = ws + PQ1_OFF;
    float* ps2 = ws + PS2_OFF;  float* pq2 = ws + PQ2_OFF;
    float* ps3 = ws + PS3_OFF;  float* pq3 = ws + PQ3_OFF;
    unsigned* bar = (unsigned*)(ws + BAR_OFF);

    __shared__ float wsb[8 * 64];   // weight slice for stages 2/3
    __shared__ float sAB[2 * 64];   // BN coeffs for stages 2/3
    __shared__ float sAB4[4];       // BN coeffs for stage 4 (2 channels)

    int t = threadIdx.x, blk = blockIdx.x;

    // ---------------- stage 1: gather + GEMM1 + partials  ||  zero-fill ----
    if (blk < 256) {
        int ob = blk & 7, pb = blk >> 3, o0 = ob * 8;
        int p  = pb * 256 + t;
        int b  = p >> 10;
        int pp = p & (NP - 1);
        int n  = idx[b * NP + pp];
        float f[C0];
#pragma unroll
        for (int c = 0; c < CIN; ++c) f[c] = points[((size_t)b * CIN + c) * N + n];
#pragma unroll
        for (int c = 0; c < NC; ++c)  f[CIN + c] = onehot[b * NC + c];
        float acc[8];
#pragma unroll
        for (int o = 0; o < 8; ++o) {
            float a = 0.f;
#pragma unroll
            for (int c = 0; c < C0; ++c) a += w1[(o0 + o) * C0 + c] * f[c];  // uniform -> s_load
            acc[o] = a;
            y1[(size_t)(o0 + o) * NPTS + p] = a;
        }
        emit_partials8(acc, o0, pb, ps1, pq1);
    } else {
        int zb = blk - 256;                       // 0..255, 1536 float4 each
        float4 z = make_float4(0.f, 0.f, 0.f, 0.f);
        float4* g = (float4*)out + (size_t)zb * 1536 + t;
#pragma unroll
        for (int i = 0; i < 6; ++i) g[i * 256] = z;
    }
    grid_bar(bar, 0);

    // ---------------- stage 2: BN1+ReLU -> GEMM2 + partials ----------------
    if (blk < 256) {
        int ob = blk & 7, pb = blk >> 3, o0 = ob * 8;
        fold_AB64(ps1, pq1, g1, b1, sAB);
        for (int i = t; i < 512; i += 256) wsb[i] = w2[o0 * 64 + i];
        __syncthreads();
        int p = pb * 256 + t;
        float acc[8] = {0.f, 0.f, 0.f, 0.f, 0.f, 0.f, 0.f, 0.f};
        for (int ch = 0; ch < 64; ch += 16) {
            float x[16];
#pragma unroll
            for (int j = 0; j < 16; ++j) {
                int c = ch + j;
                float v = y1[(size_t)c * NPTS + p] * sAB[2 * c] + sAB[2 * c + 1];
                x[j] = fmaxf(v, 0.f);
            }
#pragma unroll
            for (int o = 0; o < 8; ++o) {
                float a = 0.f;
#pragma unroll
                for (int j = 0; j < 16; ++j) a += wsb[o * 64 + ch + j] * x[j];
                acc[o] += a;
            }
        }
#pragma unroll
        for (int o = 0; o < 8; ++o) y2[(size_t)(o0 + o) * NPTS + p] = acc[o];
        emit_partials8(acc, o0, pb, ps2, pq2);
    }
    grid_bar(bar, 1);

    // ---------------- stage 3: BN2+ReLU -> GEMM3 + partials (all 512) -------
    {
        int ob = blk & 15, pb = blk >> 4, o0 = ob * 8;
        fold_AB64(ps2, pq2, g2, b2, sAB);
        for (int i = t; i < 512; i += 256) wsb[i] = w3[o0 * 64 + i];
        __syncthreads();
        int p = pb * 256 + t;
        float acc[8] = {0.f, 0.f, 0.f, 0.f, 0.f, 0.f, 0.f, 0.f};
        for (int ch = 0; ch < 64; ch += 16) {
            float x[16];
#pragma unroll
            for (int j = 0; j < 16; ++j) {
                int c = ch + j;
                float v = y2[(size_t)c * NPTS + p] * sAB[2 * c] + sAB[2 * c + 1];
                x[j] = fmaxf(v, 0.f);
            }
#pragma unroll
            for (int o = 0; o < 8; ++o) {
                float a = 0.f;
#pragma unroll
                for (int j = 0; j < 16; ++j) a += wsb[o * 64 + ch + j] * x[j];
                acc[o] += a;
            }
        }
#pragma unroll
        for (int o = 0; o < 8; ++o) y3[(size_t)(o0 + o) * NPTS + p] = acc[o];
        emit_partials8(acc, o0, pb, ps3, pq3);
    }
    grid_bar(bar, 2);

    // ---------------- stage 4: BN3+ReLU, write pooled (2 rows per block) ----
    {
        int r0 = blk * 2;              // rows r0, r0+1 of [B*M3][NP]
        int c0 = r0 & (M3 - 1);        // even; c1 = c0+1, same b
        int bb = r0 >> 7;
        if (t < 64) {
            int half = t >> 5;         // 0 -> c0, 1 -> c0+1
            int ch = c0 + half;
            int i  = t & 31;
            float s = ps3[ch * NPB + i];
            float q = pq3[ch * NPB + i];
#pragma unroll
            for (int off = 16; off; off >>= 1) {
                s += __shfl_down(s, off, 32);
                q += __shfl_down(q, off, 32);
            }
            if ((t & 31) == 0) {
                float inv_n = 1.0f / (float)NPTS;
                float mean = s * inv_n;
                float var  = q * inv_n - mean * mean;
                float A = g3[ch] * rsqrtf(var + EPS);
                sAB4[2 * half]     = A;
                sAB4[2 * half + 1] = b3[ch] - mean * A;
            }
        }
        __syncthreads();
        float A0 = sAB4[0], B0 = sAB4[1], A1 = sAB4[2], B1 = sAB4[3];
        float4* out4 = (float4*)(out + GZ_ELEMS);
        const float4 v0 = ((const float4*)(y3 + (size_t)c0 * NPTS + bb * NP))[t];
        float4 r0v;
        r0v.x = fmaxf(v0.x * A0 + B0, 0.f);
        r0v.y = fmaxf(v0.y * A0 + B0, 0.f);
        r0v.z = fmaxf(v0.z * A0 + B0, 0.f);
        r0v.w = fmaxf(v0.w * A0 + B0, 0.f);
        out4[(size_t)r0 * 256 + t] = r0v;
        const float4 v1 = ((const float4*)(y3 + (size_t)(c0 + 1) * NPTS + bb * NP))[t];
        float4 r1v;
        r1v.x = fmaxf(v1.x * A1 + B1, 0.f);
        r1v.y = fmaxf(v1.y * A1 + B1, 0.f);
        r1v.z = fmaxf(v1.z * A1 + B1, 0.f);
        r1v.w = fmaxf(v1.w * A1 + B1, 0.f);
        out4[(size_t)(r0 + 1) * 256 + t] = r1v;
    }
}

extern "C" void kernel_launch(void* const* d_in, const int* in_sizes, int n_in,
                              void* d_out, int out_size, void* d_ws, size_t ws_size,
                              hipStream_t stream) {
    const float* points = (const float*)d_in[1];
    const float* onehot = (const float*)d_in[2];
    const int*   idx    = (const int*)d_in[3];
    const float* w1 = (const float*)d_in[4];
    const float* g1 = (const float*)d_in[5];
    const float* b1 = (const float*)d_in[6];
    const float* w2 = (const float*)d_in[7];
    const float* g2 = (const float*)d_in[8];
    const float* b2 = (const float*)d_in[9];
    const float* w3 = (const float*)d_in[10];
    const float* g3 = (const float*)d_in[11];
    const float* b3 = (const float*)d_in[12];

    float* ws  = (float*)d_ws;
    unsigned* bar = (unsigned*)(ws + BAR_OFF);

    k0_init<<<1, 64, 0, stream>>>(bar);
    k_fused<<<GRID, T, 0, stream>>>(points, onehot, idx,
                                    w1, g1, b1, w2, g2, b2, w3, g3, b3,
                                    ws, (float*)d_out);
}

// Round 6
// 204.236 us; speedup vs baseline: 1.6850x; 1.6850x over previous
//
#include <hip/hip_runtime.h>

// Problem constants
constexpr int B    = 8;
constexpr int N    = 4096;
constexpr int CIN  = 6;
constexpr int NC   = 3;
constexpr int NP   = 1024;
constexpr int C0   = CIN + NC;   // 9
constexpr int M1   = 64;
constexpr int M2   = 64;
constexpr int M3   = 128;
constexpr int NPTS = B * NP;     // 8192
constexpr int NPB  = 32;         // partial blocks per channel
constexpr float EPS = 1e-5f;

constexpr int GRID = 512;        // 2 blocks/CU worst case -> all co-resident
constexpr int T    = 256;

// d_out layout: [grouped_xyz zeros: 6 MB] ++ [pooled: B*M3*NP]
constexpr int GZ_ELEMS = B * NP * 64 * 3;   // 1,572,864 floats
constexpr int GZ_F4    = GZ_ELEMS / 4;      // 393,216 float4

// d_ws layout (floats)
constexpr size_t Y1_OFF  = 0;
constexpr size_t Y2_OFF  = Y1_OFF + (size_t)M1 * NPTS;
constexpr size_t Y3_OFF  = Y2_OFF + (size_t)M2 * NPTS;
constexpr size_t PS1_OFF = Y3_OFF + (size_t)M3 * NPTS;
constexpr size_t PQ1_OFF = PS1_OFF + M1 * NPB;
constexpr size_t PS2_OFF = PQ1_OFF + M1 * NPB;
constexpr size_t PQ2_OFF = PS2_OFF + M2 * NPB;
constexpr size_t PS3_OFF = PQ2_OFF + M2 * NPB;
constexpr size_t PQ3_OFF = PS3_OFF + M3 * NPB;
constexpr size_t BAR_OFF = PQ3_OFF + M3 * NPB;   // 3 counters, 32 floats apart

// ---- node 1: zero the grid-barrier counters (d_ws is poisoned 0xAA) ----
__global__ void k0_init(unsigned* __restrict__ bar) {
    if (threadIdx.x < 128) bar[threadIdx.x] = 0u;   // covers 3 padded counters
}

// ---- device-scope grid barrier, RELAXED spin (no per-iter cache maintenance) ----
// Counter bi lives at bar[bi*32] (128 B apart -> no false sharing).
__device__ inline void grid_bar(unsigned* __restrict__ bar, int bi) {
    __syncthreads();
    if (threadIdx.x == 0) {
        unsigned* ctr = bar + bi * 32;
        __threadfence();  // release: write back our dirty L2 lines (agent scope)
        __hip_atomic_fetch_add(ctr, 1u, __ATOMIC_RELAXED, __HIP_MEMORY_SCOPE_AGENT);
        long tries = 0;
        while (__hip_atomic_load(ctr, __ATOMIC_RELAXED, __HIP_MEMORY_SCOPE_AGENT)
               < (unsigned)GRID) {
            __builtin_amdgcn_s_sleep(2);
            if (++tries > (1L << 27)) break;   // safety valve: never hang the queue
        }
        __threadfence();  // acquire: invalidate stale L1/L2 before consuming
    }
    __syncthreads();
}

// ---- deterministic per-block partial sums (8 channels) ----
__device__ inline void emit_partials8(const float (&acc)[8], int o0, int pb,
                                      float* __restrict__ ps, float* __restrict__ pq) {
    __shared__ float rs[8][4], rq[8][4];
    __syncthreads();   // guard reuse of rs/rq across calls
    float sv[8], qv[8];
#pragma unroll
    for (int o = 0; o < 8; ++o) { sv[o] = acc[o]; qv[o] = acc[o] * acc[o]; }
#pragma unroll
    for (int off = 32; off; off >>= 1) {
#pragma unroll
        for (int o = 0; o < 8; ++o) {
            sv[o] += __shfl_down(sv[o], off, 64);
            qv[o] += __shfl_down(qv[o], off, 64);
        }
    }
    int lane = threadIdx.x & 63, w = threadIdx.x >> 6;
    if (lane == 0) {
#pragma unroll
        for (int o = 0; o < 8; ++o) { rs[o][w] = sv[o]; rq[o][w] = qv[o]; }
    }
    __syncthreads();
    if (threadIdx.x < 8) {
        int o = threadIdx.x;
        float s = rs[o][0] + rs[o][1] + rs[o][2] + rs[o][3];
        float q = rq[o][0] + rq[o][1] + rq[o][2] + rq[o][3];
        ps[(o0 + o) * NPB + pb] = s;
        pq[(o0 + o) * NPB + pb] = q;
    }
}

// ---- fold 64-channel partials into per-channel A,B (threads 0..63) ----
__device__ inline void fold_AB64(const float* __restrict__ ps, const float* __restrict__ pq,
                                 const float* __restrict__ gamma, const float* __restrict__ beta,
                                 float* __restrict__ sAB) {
    int t = threadIdx.x;
    if (t < 64) {
        float s = 0.f, q = 0.f;
#pragma unroll 8
        for (int i = 0; i < NPB; ++i) { s += ps[t * NPB + i]; q += pq[t * NPB + i]; }
        float inv_n = 1.0f / (float)NPTS;
        float mean = s * inv_n;
        float var  = q * inv_n - mean * mean;
        float A = gamma[t] * rsqrtf(var + EPS);
        sAB[2 * t]     = A;
        sAB[2 * t + 1] = beta[t] - mean * A;
    }
}

// ---- the fused persistent kernel ----
__global__ __launch_bounds__(T, 2)
void k_fused(const float* __restrict__ points,
             const float* __restrict__ onehot,
             const int*   __restrict__ idx,
             const float* __restrict__ w1,
             const float* __restrict__ g1, const float* __restrict__ b1,
             const float* __restrict__ w2,
             const float* __restrict__ g2, const float* __restrict__ b2,
             const float* __restrict__ w3,
             const float* __restrict__ g3, const float* __restrict__ b3,
             float* __restrict__ ws, float* __restrict__ out) {
    float* y1  = ws + Y1_OFF;
    float* y2  = ws + Y2_OFF;
    float* y3  = ws + Y3_OFF;
    float* ps1 = ws + PS1_OFF;  float* pq1 = ws + PQ1_OFF;
    float* ps2 = ws + PS2_OFF;  float* pq2 = ws + PQ2_OFF;
    float* ps3 = ws + PS3_OFF;  float* pq3 = ws + PQ3_OFF;
    unsigned* bar = (unsigned*)(ws + BAR_OFF);

    __shared__ float wsb[8 * 64];   // weight slice for stages 2/3
    __shared__ float sAB[2 * 64];   // BN coeffs for stages 2/3
    __shared__ float sAB4[4];       // BN coeffs for stage 4 (2 channels)

    int t = threadIdx.x, blk = blockIdx.x;

    // ---------------- stage 1: gather + GEMM1 + partials  ||  zero-fill ----
    if (blk < 256) {
        int ob = blk & 7, pb = blk >> 3, o0 = ob * 8;
        int p  = pb * 256 + t;
        int b  = p >> 10;
        int pp = p & (NP - 1);
        int n  = idx[b * NP + pp];
        float f[C0];
#pragma unroll
        for (int c = 0; c < CIN; ++c) f[c] = points[((size_t)b * CIN + c) * N + n];
#pragma unroll
        for (int c = 0; c < NC; ++c)  f[CIN + c] = onehot[b * NC + c];
        float acc[8];
#pragma unroll
        for (int o = 0; o < 8; ++o) {
            float a = 0.f;
#pragma unroll
            for (int c = 0; c < C0; ++c) a += w1[(o0 + o) * C0 + c] * f[c];
            acc[o] = a;
            y1[(size_t)(o0 + o) * NPTS + p] = a;
        }
        emit_partials8(acc, o0, pb, ps1, pq1);
    } else {
        int zb = blk - 256;                       // 0..255, 1536 float4 each
        float4 z = make_float4(0.f, 0.f, 0.f, 0.f);
        float4* g = (float4*)out + (size_t)zb * 1536 + t;
#pragma unroll
        for (int i = 0; i < 6; ++i) g[i * 256] = z;
    }
    grid_bar(bar, 0);

    // ---------------- stage 2: BN1+ReLU -> GEMM2 + partials ----------------
    if (blk < 256) {
        int ob = blk & 7, pb = blk >> 3, o0 = ob * 8;
        fold_AB64(ps1, pq1, g1, b1, sAB);
        for (int i = t; i < 512; i += 256) wsb[i] = w2[o0 * 64 + i];
        __syncthreads();
        int p = pb * 256 + t;
        float acc[8] = {0.f, 0.f, 0.f, 0.f, 0.f, 0.f, 0.f, 0.f};
        for (int ch = 0; ch < 64; ch += 16) {
            float x[16];
#pragma unroll
            for (int j = 0; j < 16; ++j) {
                int c = ch + j;
                float v = y1[(size_t)c * NPTS + p] * sAB[2 * c] + sAB[2 * c + 1];
                x[j] = fmaxf(v, 0.f);
            }
#pragma unroll
            for (int o = 0; o < 8; ++o) {
                float a = 0.f;
#pragma unroll
                for (int j = 0; j < 16; ++j) a += wsb[o * 64 + ch + j] * x[j];
                acc[o] += a;
            }
        }
#pragma unroll
        for (int o = 0; o < 8; ++o) y2[(size_t)(o0 + o) * NPTS + p] = acc[o];
        emit_partials8(acc, o0, pb, ps2, pq2);
    }
    grid_bar(bar, 1);

    // ---------------- stage 3: BN2+ReLU -> GEMM3 + partials (all 512) -------
    {
        int ob = blk & 15, pb = blk >> 4, o0 = ob * 8;
        fold_AB64(ps2, pq2, g2, b2, sAB);
        for (int i = t; i < 512; i += 256) wsb[i] = w3[o0 * 64 + i];
        __syncthreads();
        int p = pb * 256 + t;
        float acc[8] = {0.f, 0.f, 0.f, 0.f, 0.f, 0.f, 0.f, 0.f};
        for (int ch = 0; ch < 64; ch += 16) {
            float x[16];
#pragma unroll
            for (int j = 0; j < 16; ++j) {
                int c = ch + j;
                float v = y2[(size_t)c * NPTS + p] * sAB[2 * c] + sAB[2 * c + 1];
                x[j] = fmaxf(v, 0.f);
            }
#pragma unroll
            for (int o = 0; o < 8; ++o) {
                float a = 0.f;
#pragma unroll
                for (int j = 0; j < 16; ++j) a += wsb[o * 64 + ch + j] * x[j];
                acc[o] += a;
            }
        }
#pragma unroll
        for (int o = 0; o < 8; ++o) y3[(size_t)(o0 + o) * NPTS + p] = acc[o];
        emit_partials8(acc, o0, pb, ps3, pq3);
    }
    grid_bar(bar, 2);

    // ---------------- stage 4: BN3+ReLU, write pooled (2 rows per block) ----
    {
        int r0 = blk * 2;              // rows r0, r0+1 of [B*M3][NP]
        int c0 = r0 & (M3 - 1);        // even; c1 = c0+1, same b
        int bb = r0 >> 7;
        if (t < 64) {
            int half = t >> 5;         // 0 -> c0, 1 -> c0+1
            int ch = c0 + half;
            int i  = t & 31;
            float s = ps3[ch * NPB + i];
            float q = pq3[ch * NPB + i];
#pragma unroll
            for (int off = 16; off; off >>= 1) {
                s += __shfl_down(s, off, 32);
                q += __shfl_down(q, off, 32);
            }
            if ((t & 31) == 0) {
                float inv_n = 1.0f / (float)NPTS;
                float mean = s * inv_n;
                float var  = q * inv_n - mean * mean;
                float A = g3[ch] * rsqrtf(var + EPS);
                sAB4[2 * half]     = A;
                sAB4[2 * half + 1] = b3[ch] - mean * A;
            }
        }
        __syncthreads();
        float A0 = sAB4[0], B0 = sAB4[1], A1 = sAB4[2], B1 = sAB4[3];
        float4* out4 = (float4*)(out + GZ_ELEMS);
        const float4 v0 = ((const float4*)(y3 + (size_t)c0 * NPTS + bb * NP))[t];
        float4 r0v;
        r0v.x = fmaxf(v0.x * A0 + B0, 0.f);
        r0v.y = fmaxf(v0.y * A0 + B0, 0.f);
        r0v.z = fmaxf(v0.z * A0 + B0, 0.f);
        r0v.w = fmaxf(v0.w * A0 + B0, 0.f);
        out4[(size_t)r0 * 256 + t] = r0v;
        const float4 v1 = ((const float4*)(y3 + (size_t)(c0 + 1) * NPTS + bb * NP))[t];
        float4 r1v;
        r1v.x = fmaxf(v1.x * A1 + B1, 0.f);
        r1v.y = fmaxf(v1.y * A1 + B1, 0.f);
        r1v.z = fmaxf(v1.z * A1 + B1, 0.f);
        r1v.w = fmaxf(v1.w * A1 + B1, 0.f);
        out4[(size_t)(r0 + 1) * 256 + t] = r1v;
    }
}

extern "C" void kernel_launch(void* const* d_in, const int* in_sizes, int n_in,
                              void* d_out, int out_size, void* d_ws, size_t ws_size,
                              hipStream_t stream) {
    const float* points = (const float*)d_in[1];
    const float* onehot = (const float*)d_in[2];
    const int*   idx    = (const int*)d_in[3];
    const float* w1 = (const float*)d_in[4];
    const float* g1 = (const float*)d_in[5];
    const float* b1 = (const float*)d_in[6];
    const float* w2 = (const float*)d_in[7];
    const float* g2 = (const float*)d_in[8];
    const float* b2 = (const float*)d_in[9];
    const float* w3 = (const float*)d_in[10];
    const float* g3 = (const float*)d_in[11];
    const float* b3 = (const float*)d_in[12];

    float* ws  = (float*)d_ws;
    unsigned* bar = (unsigned*)(ws + BAR_OFF);

    k0_init<<<1, 128, 0, stream>>>(bar);
    k_fused<<<GRID, T, 0, stream>>>(points, onehot, idx,
                                    w1, g1, b1, w2, g2, b2, w3, g3, b3,
                                    ws, (float*)d_out);
}

// Round 8
// 84.671 us; speedup vs baseline: 4.0645x; 2.4121x over previous
//
#include <hip/hip_runtime.h>

// Problem constants
constexpr int B    = 8;
constexpr int N    = 4096;
constexpr int CIN  = 6;
constexpr int NC   = 3;
constexpr int NP   = 1024;
constexpr int C0   = CIN + NC;   // 9
constexpr int M1   = 64;
constexpr int M2   = 64;
constexpr int M3   = 128;
constexpr int NPTS = B * NP;     // 8192
constexpr int NPB  = 32;         // partial blocks per channel
constexpr float EPS = 1e-5f;

constexpr int GRID = 256;        // 1 block/CU -> trivially co-resident
constexpr int T    = 256;

// native vector type usable with __builtin_nontemporal_store
typedef float f4 __attribute__((ext_vector_type(4)));

// d_out layout: [grouped_xyz zeros: 6 MB] ++ [pooled: B*M3*NP]
constexpr int GZ_ELEMS = B * NP * 64 * 3;   // 1,572,864 floats
constexpr int GZ_F4    = GZ_ELEMS / 4;      // 393,216 float4

// d_ws layout (floats)
constexpr size_t Y1_OFF  = 0;
constexpr size_t Y2_OFF  = Y1_OFF + (size_t)M1 * NPTS;
constexpr size_t Y3_OFF  = Y2_OFF + (size_t)M2 * NPTS;
constexpr size_t PS1_OFF = Y3_OFF + (size_t)M3 * NPTS;
constexpr size_t PQ1_OFF = PS1_OFF + M1 * NPB;
constexpr size_t PS2_OFF = PQ1_OFF + M1 * NPB;
constexpr size_t PQ2_OFF = PS2_OFF + M2 * NPB;
constexpr size_t PS3_OFF = PQ2_OFF + M2 * NPB;
constexpr size_t PQ3_OFF = PS3_OFF + M3 * NPB;
constexpr size_t BAR_OFF = PQ3_OFF + M3 * NPB;
// barrier region: 3 barriers x 512 uints (8 banks + master, 128B-padded)

// ---- node 1: zero the grid-barrier counters (d_ws poisoned 0xAA; also the
// fused kernel leaves counters nonzero, so re-zero every replay) ----
__global__ void k0_init(unsigned* __restrict__ bar) {
    int t = threadIdx.x;
#pragma unroll
    for (int i = 0; i < 6; ++i) bar[i * 256 + t] = 0u;   // 1536 uints
}

// ---- grid barrier: banked release-arrival, relaxed poll, NO acquire fence.
// Correctness of no-acquire: all inter-stage data is written ONCE with
// nontemporal stores (bypass L2 -> no stale copy exists anywhere) and read
// only after the barrier; kernel-entry acquire invalidated pre-kernel lines.
__device__ inline void grid_bar(unsigned* __restrict__ bar, int bi, int blk) {
    __syncthreads();
    if (threadIdx.x == 0) {
        unsigned* base   = bar + bi * 512;
        unsigned* bank   = base + (blk & 7) * 32;
        unsigned* master = base + 8 * 32;
        // RELEASE: vmcnt-drain + L2 writeback (cheap: L2 is clean, stores were nt)
        unsigned old = __hip_atomic_fetch_add(bank, 1u, __ATOMIC_RELEASE,
                                              __HIP_MEMORY_SCOPE_AGENT);
        if (old == (unsigned)(GRID / 8 - 1)) {
            __hip_atomic_fetch_add(master, 1u, __ATOMIC_RELEASE,
                                   __HIP_MEMORY_SCOPE_AGENT);
        }
        long tries = 0;
        while (__hip_atomic_load(master, __ATOMIC_RELAXED,
                                 __HIP_MEMORY_SCOPE_AGENT) < 8u) {
            __builtin_amdgcn_s_sleep(8);
            if (++tries > (1L << 26)) break;   // safety valve: never hang
        }
    }
    __syncthreads();
}

// ---- deterministic per-block partial sums (OC channels) ----
template <int OC>
__device__ inline void emit_partials(const float (&acc)[OC], int o0, int pb,
                                     float* __restrict__ ps, float* __restrict__ pq) {
    __shared__ float rs[OC][4], rq[OC][4];
    __syncthreads();   // guard shared reuse
    float sv[OC], qv[OC];
#pragma unroll
    for (int o = 0; o < OC; ++o) { sv[o] = acc[o]; qv[o] = acc[o] * acc[o]; }
#pragma unroll
    for (int off = 32; off; off >>= 1) {
#pragma unroll
        for (int o = 0; o < OC; ++o) {
            sv[o] += __shfl_down(sv[o], off, 64);
            qv[o] += __shfl_down(qv[o], off, 64);
        }
    }
    int lane = threadIdx.x & 63, w = threadIdx.x >> 6;
    if (lane == 0) {
#pragma unroll
        for (int o = 0; o < OC; ++o) { rs[o][w] = sv[o]; rq[o][w] = qv[o]; }
    }
    __syncthreads();
    if (threadIdx.x < OC) {
        int o = threadIdx.x;
        float s = rs[o][0] + rs[o][1] + rs[o][2] + rs[o][3];
        float q = rq[o][0] + rq[o][1] + rq[o][2] + rq[o][3];
        __builtin_nontemporal_store(s, &ps[(o0 + o) * NPB + pb]);
        __builtin_nontemporal_store(q, &pq[(o0 + o) * NPB + pb]);
    }
}

// ---- fold 64-channel partials into per-channel A,B (threads 0..63) ----
__device__ inline void fold_AB64(const float* __restrict__ ps, const float* __restrict__ pq,
                                 const float* __restrict__ gamma, const float* __restrict__ beta,
                                 float* __restrict__ sAB) {
    int t = threadIdx.x;
    if (t < 64) {
        float s = 0.f, q = 0.f;
#pragma unroll 8
        for (int i = 0; i < NPB; ++i) { s += ps[t * NPB + i]; q += pq[t * NPB + i]; }
        float inv_n = 1.0f / (float)NPTS;
        float mean = s * inv_n;
        float var  = q * inv_n - mean * mean;
        float A = gamma[t] * rsqrtf(var + EPS);
        sAB[2 * t]     = A;
        sAB[2 * t + 1] = beta[t] - mean * A;
    }
}

// ---- the fused persistent kernel (256 blocks, all blocks work every stage) ----
__global__ __launch_bounds__(T, 2)
void k_fused(const float* __restrict__ points,
             const float* __restrict__ onehot,
             const int*   __restrict__ idx,
             const float* __restrict__ w1,
             const float* __restrict__ g1, const float* __restrict__ b1,
             const float* __restrict__ w2,
             const float* __restrict__ g2, const float* __restrict__ b2,
             const float* __restrict__ w3,
             const float* __restrict__ g3, const float* __restrict__ b3,
             float* __restrict__ ws, float* __restrict__ out) {
    float* y1  = ws + Y1_OFF;
    float* y2  = ws + Y2_OFF;
    float* y3  = ws + Y3_OFF;
    float* ps1 = ws + PS1_OFF;  float* pq1 = ws + PQ1_OFF;
    float* ps2 = ws + PS2_OFF;  float* pq2 = ws + PQ2_OFF;
    float* ps3 = ws + PS3_OFF;  float* pq3 = ws + PQ3_OFF;
    unsigned* bar = (unsigned*)(ws + BAR_OFF);

    __shared__ float wsb[16 * 64];  // weight slice (stage 3 is the largest user)
    __shared__ float sAB[2 * 64];   // BN coeffs for stages 2/3
    __shared__ float sAB4[8];       // BN coeffs for stage 4 (4 channels)

    int t = threadIdx.x, blk = blockIdx.x;

    // ------- stage 1: zero-fill gz (nt) + gather + GEMM1 + partials -------
    {
        f4 z = {0.f, 0.f, 0.f, 0.f};
        f4* g = (f4*)out + (size_t)blk * (GZ_F4 / GRID) + t;
#pragma unroll
        for (int i = 0; i < GZ_F4 / GRID / 256; ++i)   // 6 stores
            __builtin_nontemporal_store(z, &g[i * 256]);

        int ob = blk & 7, pb = blk >> 3, o0 = ob * 8;
        int p  = pb * 256 + t;
        int b  = p >> 10;
        int pp = p & (NP - 1);
        int n  = idx[b * NP + pp];
        float f[C0];
#pragma unroll
        for (int c = 0; c < CIN; ++c) f[c] = points[((size_t)b * CIN + c) * N + n];
#pragma unroll
        for (int c = 0; c < NC; ++c)  f[CIN + c] = onehot[b * NC + c];
        float acc[8];
#pragma unroll
        for (int o = 0; o < 8; ++o) {
            float a = 0.f;
#pragma unroll
            for (int c = 0; c < C0; ++c) a += w1[(o0 + o) * C0 + c] * f[c];
            acc[o] = a;
            __builtin_nontemporal_store(a, &y1[(size_t)(o0 + o) * NPTS + p]);
        }
        emit_partials<8>(acc, o0, pb, ps1, pq1);
    }
    grid_bar(bar, 0, blk);

    // ------- stage 2: BN1+ReLU -> GEMM2 (8 out-ch/block) + partials -------
    {
        int ob = blk & 7, pb = blk >> 3, o0 = ob * 8;
        fold_AB64(ps1, pq1, g1, b1, sAB);
        for (int i = t; i < 512; i += 256) wsb[i] = w2[o0 * 64 + i];
        __syncthreads();
        int p = pb * 256 + t;
        float acc[8] = {0.f, 0.f, 0.f, 0.f, 0.f, 0.f, 0.f, 0.f};
        for (int ch = 0; ch < 64; ch += 16) {
            float x[16];
#pragma unroll
            for (int j = 0; j < 16; ++j) {
                int c = ch + j;
                float v = y1[(size_t)c * NPTS + p] * sAB[2 * c] + sAB[2 * c + 1];
                x[j] = fmaxf(v, 0.f);
            }
#pragma unroll
            for (int o = 0; o < 8; ++o) {
                float a = 0.f;
#pragma unroll
                for (int j = 0; j < 16; ++j) a += wsb[o * 64 + ch + j] * x[j];
                acc[o] += a;
            }
        }
#pragma unroll
        for (int o = 0; o < 8; ++o)
            __builtin_nontemporal_store(acc[o], &y2[(size_t)(o0 + o) * NPTS + p]);
        emit_partials<8>(acc, o0, pb, ps2, pq2);
    }
    grid_bar(bar, 1, blk);

    // ------- stage 3: BN2+ReLU -> GEMM3 (16 out-ch/block) + partials -------
    {
        int ob = blk & 7, pb = blk >> 3, o0 = ob * 16;
        fold_AB64(ps2, pq2, g2, b2, sAB);
        __syncthreads();
        for (int i = t; i < 1024; i += 256) wsb[i] = w3[o0 * 64 + i];
        __syncthreads();
        int p = pb * 256 + t;
        float acc[16];
#pragma unroll
        for (int o = 0; o < 16; ++o) acc[o] = 0.f;
        for (int ch = 0; ch < 64; ch += 16) {
            float x[16];
#pragma unroll
            for (int j = 0; j < 16; ++j) {
                int c = ch + j;
                float v = y2[(size_t)c * NPTS + p] * sAB[2 * c] + sAB[2 * c + 1];
                x[j] = fmaxf(v, 0.f);
            }
#pragma unroll
            for (int o = 0; o < 16; ++o) {
                float a = 0.f;
#pragma unroll
                for (int j = 0; j < 16; ++j) a += wsb[o * 64 + ch + j] * x[j];
                acc[o] += a;
            }
        }
#pragma unroll
        for (int o = 0; o < 16; ++o)
            __builtin_nontemporal_store(acc[o], &y3[(size_t)(o0 + o) * NPTS + p]);
        emit_partials<16>(acc, o0, pb, ps3, pq3);
    }
    grid_bar(bar, 2, blk);

    // ------- stage 4: BN3+ReLU, write pooled (4 rows per block, nt) -------
    {
        int r0 = blk * 4;              // rows r0..r0+3 of [B*M3][NP]
        int c0 = r0 & (M3 - 1);        // 4-aligned, no wrap
        int bb = r0 >> 7;
        if (t < 128) {
            int j  = t >> 5;           // channel c0+j
            int ch = c0 + j;
            int i  = t & 31;
            float s = ps3[ch * NPB + i];
            float q = pq3[ch * NPB + i];
#pragma unroll
            for (int off = 16; off; off >>= 1) {
                s += __shfl_down(s, off, 32);
                q += __shfl_down(q, off, 32);
            }
            if ((t & 31) == 0) {
                float inv_n = 1.0f / (float)NPTS;
                float mean = s * inv_n;
                float var  = q * inv_n - mean * mean;
                float A = g3[ch] * rsqrtf(var + EPS);
                sAB4[2 * j]     = A;
                sAB4[2 * j + 1] = b3[ch] - mean * A;
            }
        }
        __syncthreads();
        f4* out4 = (f4*)(out + GZ_ELEMS);
#pragma unroll
        for (int j = 0; j < 4; ++j) {
            float A = sAB4[2 * j], Bb = sAB4[2 * j + 1];
            const float4 v = ((const float4*)(y3 + (size_t)(c0 + j) * NPTS + bb * NP))[t];
            f4 r;
            r.x = fmaxf(v.x * A + Bb, 0.f);
            r.y = fmaxf(v.y * A + Bb, 0.f);
            r.z = fmaxf(v.z * A + Bb, 0.f);
            r.w = fmaxf(v.w * A + Bb, 0.f);
            __builtin_nontemporal_store(r, &out4[(size_t)(r0 + j) * 256 + t]);
        }
    }
}

extern "C" void kernel_launch(void* const* d_in, const int* in_sizes, int n_in,
                              void* d_out, int out_size, void* d_ws, size_t ws_size,
                              hipStream_t stream) {
    const float* points = (const float*)d_in[1];
    const float* onehot = (const float*)d_in[2];
    const int*   idx    = (const int*)d_in[3];
    const float* w1 = (const float*)d_in[4];
    const float* g1 = (const float*)d_in[5];
    const float* b1 = (const float*)d_in[6];
    const float* w2 = (const float*)d_in[7];
    const float* g2 = (const float*)d_in[8];
    const float* b2 = (const float*)d_in[9];
    const float* w3 = (const float*)d_in[10];
    const float* g3 = (const float*)d_in[11];
    const float* b3 = (const float*)d_in[12];

    float* ws  = (float*)d_ws;
    unsigned* bar = (unsigned*)(ws + BAR_OFF);

    k0_init<<<1, 256, 0, stream>>>(bar);
    k_fused<<<GRID, T, 0, stream>>>(points, onehot, idx,
                                    w1, g1, b1, w2, g2, b2, w3, g3, b3,
                                    ws, (float*)d_out);
}

// Round 9
// 79.282 us; speedup vs baseline: 4.3408x; 1.0680x over previous
//
#include <hip/hip_runtime.h>

// Problem constants
constexpr int B    = 8;
constexpr int N    = 4096;
constexpr int CIN  = 6;
constexpr int NC   = 3;
constexpr int NP   = 1024;
constexpr int C0   = CIN + NC;   // 9
constexpr int M1   = 64;
constexpr int M2   = 64;
constexpr int M3   = 128;
constexpr int NPTS = B * NP;     // 8192
constexpr int NPB  = 32;         // partial blocks per channel
constexpr float EPS = 1e-5f;

constexpr int GRID = 256;        // 1 block/CU -> trivially co-resident
constexpr int T    = 256;

// native vector type usable with __builtin_nontemporal_store
typedef float f4 __attribute__((ext_vector_type(4)));

// d_out layout: [grouped_xyz zeros: 6 MB] ++ [pooled: B*M3*NP]
constexpr int GZ_ELEMS = B * NP * 64 * 3;   // 1,572,864 floats
constexpr int GZ_F4    = GZ_ELEMS / 4;      // 393,216 float4

// d_ws layout (floats)
constexpr size_t Y1_OFF  = 0;
constexpr size_t Y2_OFF  = Y1_OFF + (size_t)M1 * NPTS;
constexpr size_t Y3_OFF  = Y2_OFF + (size_t)M2 * NPTS;
constexpr size_t PS1_OFF = Y3_OFF + (size_t)M3 * NPTS;
constexpr size_t PQ1_OFF = PS1_OFF + M1 * NPB;
constexpr size_t PS2_OFF = PQ1_OFF + M1 * NPB;
constexpr size_t PQ2_OFF = PS2_OFF + M2 * NPB;
constexpr size_t PS3_OFF = PQ2_OFF + M2 * NPB;
constexpr size_t PQ3_OFF = PS3_OFF + M3 * NPB;
constexpr size_t BAR_OFF = PQ3_OFF + M3 * NPB;
// barrier region per barrier (512 uints, 128B-padded slots):
//   +0 garr, +32 master, +64 present, +96+x*32 elect[x] (x=0..7)

// ---- node 1: zero the grid-barrier counters ----
__global__ void k0_init(unsigned* __restrict__ bar) {
    int t = threadIdx.x;
#pragma unroll
    for (int i = 0; i < 6; ++i) bar[i * 256 + t] = 0u;   // 1536 uints
}

// ---- hardware XCD id (0..7) — wave-uniform ----
__device__ inline unsigned xcc_id() {
    unsigned x;
    asm volatile("s_getreg_b32 %0, hwreg(HW_REG_XCC_ID)" : "=s"(x));
    return x & 7u;
}

// ---- grid barrier with ONE L2-writeback per XCD (leader release) ----
// All blocks: __syncthreads() has already drained each wave's vmcnt, so all
// prior stores are at least in the local XCD L2 (nt stores possibly past it).
// Arrivals are RELAXED (no cache maintenance). The first arriver per XCD
// (real HW_REG_XCC_ID, not blockIdx heuristics) waits for all GRID arrivals,
// then does a single RELEASE fetch_add -> one buffer_wbl2 flushing its XCD's
// L2 (covers every block on that XCD). Readers poll master == present.
__device__ inline void grid_bar(unsigned* __restrict__ bar, int bi) {
    __syncthreads();   // exec sync + per-wave vmcnt drain
    if (threadIdx.x == 0) {
        unsigned* base    = bar + bi * 512;
        unsigned* garr    = base;
        unsigned* master  = base + 32;
        unsigned* present = base + 64;
        unsigned  x       = xcc_id();
        unsigned* elect   = base + 96 + x * 32;

        unsigned e = __hip_atomic_fetch_add(elect, 1u, __ATOMIC_RELAXED,
                                            __HIP_MEMORY_SCOPE_AGENT);
        __hip_atomic_fetch_add(garr, 1u, __ATOMIC_RELAXED,
                               __HIP_MEMORY_SCOPE_AGENT);
        long tries = 0;
        if (e == 0) {   // XCD leader for this barrier
            __hip_atomic_fetch_add(present, 1u, __ATOMIC_RELAXED,
                                   __HIP_MEMORY_SCOPE_AGENT);
            while (__hip_atomic_load(garr, __ATOMIC_RELAXED,
                                     __HIP_MEMORY_SCOPE_AGENT) < (unsigned)GRID) {
                __builtin_amdgcn_s_sleep(2);
                if (++tries > (1L << 26)) break;
            }
            // all arrivals done -> all same-XCD stores sit in this L2; flush once
            __hip_atomic_fetch_add(master, 1u, __ATOMIC_RELEASE,
                                   __HIP_MEMORY_SCOPE_AGENT);
        }
        // wait for every XCD's leader to have flushed
        unsigned m;
        tries = 0;
        while ((m = __hip_atomic_load(master, __ATOMIC_RELAXED,
                                      __HIP_MEMORY_SCOPE_AGENT)) == 0u) {
            __builtin_amdgcn_s_sleep(2);
            if (++tries > (1L << 26)) break;
        }
        // master>=1 implies garr==GRID was observed -> present is final
        unsigned P = __hip_atomic_load(present, __ATOMIC_RELAXED,
                                       __HIP_MEMORY_SCOPE_AGENT);
        tries = 0;
        while (m < P) {
            __builtin_amdgcn_s_sleep(2);
            m = __hip_atomic_load(master, __ATOMIC_RELAXED,
                                  __HIP_MEMORY_SCOPE_AGENT);
            if (++tries > (1L << 26)) break;
        }
    }
    __syncthreads();
}

// ---- deterministic per-block partial sums (OC channels) ----
template <int OC>
__device__ inline void emit_partials(const float (&acc)[OC], int o0, int pb,
                                     float* __restrict__ ps, float* __restrict__ pq) {
    __shared__ float rs[OC][4], rq[OC][4];
    __syncthreads();   // guard shared reuse
    float sv[OC], qv[OC];
#pragma unroll
    for (int o = 0; o < OC; ++o) { sv[o] = acc[o]; qv[o] = acc[o] * acc[o]; }
#pragma unroll
    for (int off = 32; off; off >>= 1) {
#pragma unroll
        for (int o = 0; o < OC; ++o) {
            sv[o] += __shfl_down(sv[o], off, 64);
            qv[o] += __shfl_down(qv[o], off, 64);
        }
    }
    int lane = threadIdx.x & 63, w = threadIdx.x >> 6;
    if (lane == 0) {
#pragma unroll
        for (int o = 0; o < OC; ++o) { rs[o][w] = sv[o]; rq[o][w] = qv[o]; }
    }
    __syncthreads();
    if (threadIdx.x < OC) {
        int o = threadIdx.x;
        float s = rs[o][0] + rs[o][1] + rs[o][2] + rs[o][3];
        float q = rq[o][0] + rq[o][1] + rq[o][2] + rq[o][3];
        __builtin_nontemporal_store(s, &ps[(o0 + o) * NPB + pb]);
        __builtin_nontemporal_store(q, &pq[(o0 + o) * NPB + pb]);
    }
}

// ---- fold 64-channel partials into per-channel A,B (threads 0..63) ----
__device__ inline void fold_AB64(const float* __restrict__ ps, const float* __restrict__ pq,
                                 const float* __restrict__ gamma, const float* __restrict__ beta,
                                 float* __restrict__ sAB) {
    int t = threadIdx.x;
    if (t < 64) {
        float s = 0.f, q = 0.f;
#pragma unroll 8
        for (int i = 0; i < NPB; ++i) { s += ps[t * NPB + i]; q += pq[t * NPB + i]; }
        float inv_n = 1.0f / (float)NPTS;
        float mean = s * inv_n;
        float var  = q * inv_n - mean * mean;
        float A = gamma[t] * rsqrtf(var + EPS);
        sAB[2 * t]     = A;
        sAB[2 * t + 1] = beta[t] - mean * A;
    }
}

// ---- the fused persistent kernel (256 blocks, all blocks work every stage) ----
__global__ __launch_bounds__(T, 2)
void k_fused(const float* __restrict__ points,
             const float* __restrict__ onehot,
             const int*   __restrict__ idx,
             const float* __restrict__ w1,
             const float* __restrict__ g1, const float* __restrict__ b1,
             const float* __restrict__ w2,
             const float* __restrict__ g2, const float* __restrict__ b2,
             const float* __restrict__ w3,
             const float* __restrict__ g3, const float* __restrict__ b3,
             float* __restrict__ ws, float* __restrict__ out) {
    float* y1  = ws + Y1_OFF;
    float* y2  = ws + Y2_OFF;
    float* y3  = ws + Y3_OFF;
    float* ps1 = ws + PS1_OFF;  float* pq1 = ws + PQ1_OFF;
    float* ps2 = ws + PS2_OFF;  float* pq2 = ws + PQ2_OFF;
    float* ps3 = ws + PS3_OFF;  float* pq3 = ws + PQ3_OFF;
    unsigned* bar = (unsigned*)(ws + BAR_OFF);

    __shared__ float wsb[16 * 64];  // weight slice (stage 3 is the largest user)
    __shared__ float sAB[2 * 64];   // BN coeffs for stages 2/3
    __shared__ float sAB4[8];       // BN coeffs for stage 4 (4 channels)

    int t = threadIdx.x, blk = blockIdx.x;

    // ------- stage 1: zero-fill gz (nt) + gather + GEMM1 + partials -------
    {
        f4 z = {0.f, 0.f, 0.f, 0.f};
        f4* g = (f4*)out + (size_t)blk * (GZ_F4 / GRID) + t;
#pragma unroll
        for (int i = 0; i < GZ_F4 / GRID / 256; ++i)   // 6 stores
            __builtin_nontemporal_store(z, &g[i * 256]);

        int ob = blk & 7, pb = blk >> 3, o0 = ob * 8;
        int p  = pb * 256 + t;
        int b  = p >> 10;
        int pp = p & (NP - 1);
        int n  = idx[b * NP + pp];
        float f[C0];
#pragma unroll
        for (int c = 0; c < CIN; ++c) f[c] = points[((size_t)b * CIN + c) * N + n];
#pragma unroll
        for (int c = 0; c < NC; ++c)  f[CIN + c] = onehot[b * NC + c];
        float acc[8];
#pragma unroll
        for (int o = 0; o < 8; ++o) {
            float a = 0.f;
#pragma unroll
            for (int c = 0; c < C0; ++c) a += w1[(o0 + o) * C0 + c] * f[c];
            acc[o] = a;
            __builtin_nontemporal_store(a, &y1[(size_t)(o0 + o) * NPTS + p]);
        }
        emit_partials<8>(acc, o0, pb, ps1, pq1);
    }
    grid_bar(bar, 0);

    // ------- stage 2: BN1+ReLU -> GEMM2 (8 out-ch/block) + partials -------
    {
        int ob = blk & 7, pb = blk >> 3, o0 = ob * 8;
        fold_AB64(ps1, pq1, g1, b1, sAB);
        for (int i = t; i < 512; i += 256) wsb[i] = w2[o0 * 64 + i];
        __syncthreads();
        int p = pb * 256 + t;
        float acc[8] = {0.f, 0.f, 0.f, 0.f, 0.f, 0.f, 0.f, 0.f};
        for (int ch = 0; ch < 64; ch += 16) {
            float x[16];
#pragma unroll
            for (int j = 0; j < 16; ++j) {
                int c = ch + j;
                float v = y1[(size_t)c * NPTS + p] * sAB[2 * c] + sAB[2 * c + 1];
                x[j] = fmaxf(v, 0.f);
            }
#pragma unroll
            for (int o = 0; o < 8; ++o) {
                float a = 0.f;
#pragma unroll
                for (int j = 0; j < 16; ++j) a += wsb[o * 64 + ch + j] * x[j];
                acc[o] += a;
            }
        }
#pragma unroll
        for (int o = 0; o < 8; ++o)
            __builtin_nontemporal_store(acc[o], &y2[(size_t)(o0 + o) * NPTS + p]);
        emit_partials<8>(acc, o0, pb, ps2, pq2);
    }
    grid_bar(bar, 1);

    // ------- stage 3: BN2+ReLU -> GEMM3 (16 out-ch/block) + partials -------
    {
        int ob = blk & 7, pb = blk >> 3, o0 = ob * 16;
        fold_AB64(ps2, pq2, g2, b2, sAB);
        __syncthreads();
        for (int i = t; i < 1024; i += 256) wsb[i] = w3[o0 * 64 + i];
        __syncthreads();
        int p = pb * 256 + t;
        float acc[16];
#pragma unroll
        for (int o = 0; o < 16; ++o) acc[o] = 0.f;
        for (int ch = 0; ch < 64; ch += 16) {
            float x[16];
#pragma unroll
            for (int j = 0; j < 16; ++j) {
                int c = ch + j;
                float v = y2[(size_t)c * NPTS + p] * sAB[2 * c] + sAB[2 * c + 1];
                x[j] = fmaxf(v, 0.f);
            }
#pragma unroll
            for (int o = 0; o < 16; ++o) {
                float a = 0.f;
#pragma unroll
                for (int j = 0; j < 16; ++j) a += wsb[o * 64 + ch + j] * x[j];
                acc[o] += a;
            }
        }
#pragma unroll
        for (int o = 0; o < 16; ++o)
            __builtin_nontemporal_store(acc[o], &y3[(size_t)(o0 + o) * NPTS + p]);
        emit_partials<16>(acc, o0, pb, ps3, pq3);
    }
    grid_bar(bar, 2);

    // ------- stage 4: BN3+ReLU, write pooled (4 rows per block, nt) -------
    {
        int r0 = blk * 4;              // rows r0..r0+3 of [B*M3][NP]
        int c0 = r0 & (M3 - 1);        // 4-aligned, no wrap
        int bb = r0 >> 7;
        if (t < 128) {
            int j  = t >> 5;           // channel c0+j
            int ch = c0 + j;
            int i  = t & 31;
            float s = ps3[ch * NPB + i];
            float q = pq3[ch * NPB + i];
#pragma unroll
            for (int off = 16; off; off >>= 1) {
                s += __shfl_down(s, off, 32);
                q += __shfl_down(q, off, 32);
            }
            if ((t & 31) == 0) {
                float inv_n = 1.0f / (float)NPTS;
                float mean = s * inv_n;
                float var  = q * inv_n - mean * mean;
                float A = g3[ch] * rsqrtf(var + EPS);
                sAB4[2 * j]     = A;
                sAB4[2 * j + 1] = b3[ch] - mean * A;
            }
        }
        __syncthreads();
        f4* out4 = (f4*)(out + GZ_ELEMS);
#pragma unroll
        for (int j = 0; j < 4; ++j) {
            float A = sAB4[2 * j], Bb = sAB4[2 * j + 1];
            const float4 v = ((const float4*)(y3 + (size_t)(c0 + j) * NPTS + bb * NP))[t];
            f4 r;
            r.x = fmaxf(v.x * A + Bb, 0.f);
            r.y = fmaxf(v.y * A + Bb, 0.f);
            r.z = fmaxf(v.z * A + Bb, 0.f);
            r.w = fmaxf(v.w * A + Bb, 0.f);
            __builtin_nontemporal_store(r, &out4[(size_t)(r0 + j) * 256 + t]);
        }
    }
}

extern "C" void kernel_launch(void* const* d_in, const int* in_sizes, int n_in,
                              void* d_out, int out_size, void* d_ws, size_t ws_size,
                              hipStream_t stream) {
    const float* points = (const float*)d_in[1];
    const float* onehot = (const float*)d_in[2];
    const int*   idx    = (const int*)d_in[3];
    const float* w1 = (const float*)d_in[4];
    const float* g1 = (const float*)d_in[5];
    const float* b1 = (const float*)d_in[6];
    const float* w2 = (const float*)d_in[7];
    const float* g2 = (const float*)d_in[8];
    const float* b2 = (const float*)d_in[9];
    const float* w3 = (const float*)d_in[10];
    const float* g3 = (const float*)d_in[11];
    const float* b3 = (const float*)d_in[12];

    float* ws  = (float*)d_ws;
    unsigned* bar = (unsigned*)(ws + BAR_OFF);

    k0_init<<<1, 256, 0, stream>>>(bar);
    k_fused<<<GRID, T, 0, stream>>>(points, onehot, idx,
                                    w1, g1, b1, w2, g2, b2, w3, g3, b3,
                                    ws, (float*)d_out);
}